// Round 17
// baseline (127.523 us; speedup 1.0000x reference)
//
#include <hip/hip_runtime.h>

typedef unsigned int uint;
typedef unsigned short ushort;
typedef __attribute__((ext_vector_type(8))) short short8;
typedef __attribute__((ext_vector_type(4))) float f32x4;

#define DEV static __device__ __forceinline__

DEV float bf_lo(uint v) { return __uint_as_float(v << 16); }
DEV float bf_hi(uint v) { return __uint_as_float(v & 0xffff0000u); }
DEV ushort f2bf(float f) {
    uint u = __float_as_uint(f);
    u += 0x7fffu + ((u >> 16) & 1u);   // round-to-nearest-even
    return (ushort)(u >> 16);
}
DEV void stC(float* p, float v) { *p = v; }
DEV void stC(ushort* p, float v) { *p = f2bf(v); }

// ---------------------------------------------------------------------------
// 64x64 tiled transpose body (in fp32 [R][C] -> out [C][R] fp32/bf16)
// ---------------------------------------------------------------------------
template <typename OT>
DEV void transp_body(float (*tile)[65], const float* __restrict__ in,
                     OT* __restrict__ out, int R, int C, int bid, int t)
{
    const int nbx = C >> 6;
    const int bx = bid % nbx, by = bid / nbx;
#pragma unroll
    for (int it = 0; it < 4; ++it) {
        int idx = it * 256 + t;
        int rr = idx >> 4, cc4 = (idx & 15) * 4;
        float4 v = *reinterpret_cast<const float4*>(in + (size_t)(by * 64 + rr) * C + bx * 64 + cc4);
        tile[cc4][rr] = v.x; tile[cc4 + 1][rr] = v.y;
        tile[cc4 + 2][rr] = v.z; tile[cc4 + 3][rr] = v.w;
    }
    __syncthreads();
#pragma unroll
    for (int it = 0; it < 4; ++it) {
        int idx = it * 256 + t;
        int cc = idx >> 4, rr4 = (idx & 15) * 4;
        OT* po = out + (size_t)(bx * 64 + cc) * R + by * 64 + rr4;
        if constexpr (__is_same(OT, float)) {
            float4 o = { tile[cc][rr4], tile[cc][rr4 + 1], tile[cc][rr4 + 2], tile[cc][rr4 + 3] };
            *reinterpret_cast<float4*>(po) = o;
        } else {
            ushort4 o = { f2bf(tile[cc][rr4]), f2bf(tile[cc][rr4 + 1]),
                          f2bf(tile[cc][rr4 + 2]), f2bf(tile[cc][rr4 + 3]) };
            *reinterpret_cast<ushort4*>(po) = o;
        }
    }
}

// ---------------------------------------------------------------------------
// Prep stage 1: [zero cntd] [f2bf feat] [transp Wo] [transp W1] [transp W2]
// ---------------------------------------------------------------------------
__global__ __launch_bounds__(256) void prep1_kernel(
    int4* __restrict__ cntd4, int nz,
    const float* __restrict__ feat, ushort* __restrict__ featbf,
    const float* __restrict__ Wo, float* __restrict__ WoT,
    const float* __restrict__ W1, ushort* __restrict__ W1T,
    const float* __restrict__ W2, ushort* __restrict__ W2T, int N)
{
    __shared__ float tile[64][65];
    const int zb = (nz + 255) / 256;
    const int nf = (N * 32 + 255) / 256;
    const int b = blockIdx.x, t = threadIdx.x;
    if (b < zb) {
        int i = b * 256 + t;
        if (i < nz) cntd4[i] = int4{0, 0, 0, 0};
    } else if (b < zb + nf) {
        int i = (b - zb) * 256 + t;
        if (i >= N * 32) return;
        float4 v = reinterpret_cast<const float4*>(feat)[i];
        ushort4 o;
        o.x = f2bf(v.x); o.y = f2bf(v.y); o.z = f2bf(v.z); o.w = f2bf(v.w);
        reinterpret_cast<ushort4*>(featbf)[i] = o;
    } else if (b < zb + nf + 32) {
        transp_body<float>(tile, Wo, WoT, 1024, 128, b - zb - nf, t);
    } else if (b < zb + nf + 48) {
        transp_body<ushort>(tile, W1, W1T, 128, 512, b - zb - nf - 32, t);
    } else {
        transp_body<ushort>(tile, W2, W2T, 512, 128, b - zb - nf - 48, t);
    }
}

// ---------------------------------------------------------------------------
// Merged: [hist: dst histogram] blocks [0,eb) + [mpt: MFMA build] 16 blocks.
// part0 -> MG[(h*128+j)*128 + i] = M_h[i][j]      (B^T for G gemm, 1024x128)
// part1 -> PT[j*1024 + h*128 + i] = P_h[i][j]     (B^T for Y gemm, 128x1024)
// ---------------------------------------------------------------------------
__global__ __launch_bounds__(256) void hist_mpt_kernel(
    const int* __restrict__ dst, int* __restrict__ cntd, int E, int eb,
    const float* __restrict__ Wq, const float* __restrict__ Wk,
    const float* __restrict__ Wv, const float* __restrict__ WoT,
    ushort* __restrict__ MG, ushort* __restrict__ PT)
{
    __shared__ char lds[65536];
    const int b = blockIdx.x, t = threadIdx.x;
    if (b < eb) {
        int e = b * 256 + t;
        if (e < E) atomicAdd(&cntd[dst[e]], 1);
        return;
    }
    char* As = lds;            // 128 rows(j) x 256B (128 bf16), XOR swizzled
    char* Bs = lds + 32768;    // 128 rows(i) x 256B

    const int mb = b - eb;
    const int part = mb >> 3, h = mb & 7;
    const int lane = t & 63, w = t >> 6;
    const int frow = lane & 15, kgrp = lane >> 4;

    const float* Asrc = part ? WoT : Wk;
    const float* Bsrc = part ? Wv : Wq;
    const float ascale = part ? 1.f : 0.08838834764831845f;

#pragma unroll
    for (int it = 0; it < 16; ++it) {
        int idx = it * 256 + t;
        int r = idx >> 5, c4 = (idx & 31) * 4;
        size_t goff = (size_t)r * 1024 + h * 128 + c4;
        float4 va = *reinterpret_cast<const float4*>(Asrc + goff);
        ushort4 ua = { f2bf(va.x * ascale), f2bf(va.y * ascale),
                       f2bf(va.z * ascale), f2bf(va.w * ascale) };
        *reinterpret_cast<ushort4*>(&As[r * 256 + ((c4 * 2) ^ ((r & 7) << 4))]) = ua;
        float4 vb = *reinterpret_cast<const float4*>(Bsrc + goff);
        ushort4 ub = { f2bf(vb.x), f2bf(vb.y), f2bf(vb.z), f2bf(vb.w) };
        *reinterpret_cast<ushort4*>(&Bs[r * 256 + ((c4 * 2) ^ ((r & 7) << 4))]) = ub;
    }
    __syncthreads();

    f32x4 acc[2][8] = {};
#pragma unroll
    for (int ks = 0; ks < 4; ++ks) {
        int koff = ks * 64 + kgrp * 16;
        short8 bfr[8];
#pragma unroll
        for (int fn = 0; fn < 8; ++fn) {
            int col = fn * 16 + frow;
            bfr[fn] = *reinterpret_cast<const short8*>(&Bs[col * 256 + (koff ^ ((col & 7) << 4))]);
        }
#pragma unroll
        for (int fm = 0; fm < 2; ++fm) {
            int row = w * 32 + fm * 16 + frow;
            short8 a = *reinterpret_cast<const short8*>(&As[row * 256 + (koff ^ ((row & 7) << 4))]);
#pragma unroll
            for (int fn = 0; fn < 8; ++fn)
                acc[fm][fn] = __builtin_amdgcn_mfma_f32_16x16x32_bf16(a, bfr[fn], acc[fm][fn], 0, 0, 0);
        }
    }

#pragma unroll
    for (int fm = 0; fm < 2; ++fm)
#pragma unroll
        for (int fn = 0; fn < 8; ++fn)
#pragma unroll
            for (int r = 0; r < 4; ++r) {
                int j = w * 32 + fm * 16 + kgrp * 4 + r;
                int i = fn * 16 + frow;
                if (part == 0)
                    MG[((size_t)h * 128 + j) * 128 + i] = f2bf(acc[fm][fn][r]);
                else
                    PT[(size_t)j * 1024 + h * 128 + i] = f2bf(acc[fm][fn][r]);
            }
}

// ---------------------------------------------------------------------------
// CSR scan (dst only), 1024 threads
// ---------------------------------------------------------------------------
__global__ __launch_bounds__(1024) void scan1_kernel(
    const int* __restrict__ cntd, int* __restrict__ offd, int* __restrict__ curd, int N)
{
    __shared__ int ls[1024];
    const int t = threadIdx.x;
    const int chunk = (N + 1023) >> 10;
    int base = t * chunk;
    int s = 0;
    for (int i = 0; i < chunk; ++i) {
        int idx = base + i;
        if (idx < N) s += cntd[idx];
    }
    ls[t] = s;
    __syncthreads();
    for (int d = 1; d < 1024; d <<= 1) {
        int v = (t >= d) ? ls[t - d] : 0;
        __syncthreads();
        ls[t] += v;
        __syncthreads();
    }
    int run = t ? ls[t - 1] : 0;
    for (int i = 0; i < chunk; ++i) {
        int idx = base + i;
        if (idx < N) {
            offd[idx] = run;
            curd[idx] = run;
            run += cntd[idx];
        }
    }
    if (t == 1023) offd[N] = run;
}

// ---------------------------------------------------------------------------
// Merged: [G gemm: blocks [0,nbg)] + [scat: blocks [nbg, nbg+eb)].
// G: C(M,1024) = featbf(M,128) @ MG(1024,128)^T, BK=64 loop, 128x128 tile.
// ---------------------------------------------------------------------------
__global__ __launch_bounds__(256) void gvo_scat_kernel(
    const ushort* __restrict__ A, const ushort* __restrict__ BT,
    ushort* __restrict__ C, int M, int nbg,
    const int* __restrict__ src, const int* __restrict__ dst,
    int* __restrict__ curd, int* __restrict__ src_d, int E)
{
    __shared__ char lds[32768];
    const int b = blockIdx.x, t = threadIdx.x;

    if (b >= nbg) {
        int e = (b - nbg) * 256 + t;
        if (e >= E) return;
        int s = src[e], d = dst[e];
        int pd = atomicAdd(&curd[d], 1);
        src_d[pd] = s;
        return;
    }

    char* AsB = lds;            // 128 rows x 128B, XOR swizzled
    char* BsB = lds + 16384;    // 128 rows x 128B
    const int m0 = (b >> 3) * 128;
    const int n0 = (b & 7) * 128;
    const int lane = t & 63, wid = t >> 6;
    const int wm = wid >> 1, wn = wid & 1;
    const int frow = lane & 15, kgrp = lane >> 4;

    f32x4 acc[4][4] = {};

    for (int kk = 0; kk < 128; kk += 64) {
#pragma unroll
        for (int it = 0; it < 4; ++it) {
            int q = it * 256 + t;
            int r = q >> 3, c8 = (q & 7) * 8;
            int gm = m0 + r;
            short8 v = {};
            if (gm < M) v = *reinterpret_cast<const short8*>(&A[(size_t)gm * 128 + kk + c8]);
            *reinterpret_cast<short8*>(&AsB[r * 128 + ((c8 * 2) ^ ((r & 7) << 4))]) = v;
        }
#pragma unroll
        for (int it = 0; it < 4; ++it) {
            int q = it * 256 + t;
            int r = q >> 3, c8 = (q & 7) * 8;
            short8 v = *reinterpret_cast<const short8*>(&BT[(size_t)(n0 + r) * 128 + kk + c8]);
            *reinterpret_cast<short8*>(&BsB[r * 128 + ((c8 * 2) ^ ((r & 7) << 4))]) = v;
        }
        __syncthreads();
#pragma unroll
        for (int kp = 0; kp < 2; ++kp) {
            const int koffb = kp * 64 + kgrp * 16;
            short8 bb[4];
#pragma unroll
            for (int fn = 0; fn < 4; ++fn) {
                int col = wn * 64 + fn * 16 + frow;
                bb[fn] = *reinterpret_cast<const short8*>(&BsB[col * 128 + (koffb ^ ((col & 7) << 4))]);
            }
#pragma unroll
            for (int fm = 0; fm < 4; ++fm) {
                int row = wm * 64 + fm * 16 + frow;
                short8 a = *reinterpret_cast<const short8*>(&AsB[row * 128 + (koffb ^ ((row & 7) << 4))]);
#pragma unroll
                for (int fn = 0; fn < 4; ++fn)
                    acc[fm][fn] = __builtin_amdgcn_mfma_f32_16x16x32_bf16(a, bb[fn], acc[fm][fn], 0, 0, 0);
            }
        }
        __syncthreads();
    }

#pragma unroll
    for (int fm = 0; fm < 4; ++fm)
#pragma unroll
        for (int fn = 0; fn < 4; ++fn)
#pragma unroll
            for (int r = 0; r < 4; ++r) {
                int gm = m0 + wm * 64 + fm * 16 + kgrp * 4 + r;
                int gn = n0 + wn * 64 + fn * 16 + frow;
                if (gm >= M) continue;
                stC(&C[(size_t)gm * 1024 + gn], acc[fm][fn][r]);
            }
}

// ---------------------------------------------------------------------------
// Fused edge phase, ONE WAVE PER DST, zero barriers, NO V GATHER.
// Per 16-edge tile: logits via 4x mfma (A = G[d] heads, B = feat[src_e]);
// exp; den in regs; Y[d,h,:] += ex_eh * feat[src_e,:]  (feat re-read L1-hot).
// Final: Y row scaled by 1/den_h, written bf16. (agg = Y @ [P_h] done later.)
// ---------------------------------------------------------------------------
__global__ __launch_bounds__(256) void edge_fused_kernel(
    const ushort* __restrict__ featbf, const ushort* __restrict__ G,
    const int* __restrict__ src_d, const int* __restrict__ offd,
    ushort* __restrict__ Y, int N)
{
    __shared__ float exl[4][16][8];
    __shared__ int   srcl[4][16];

    const int t = threadIdx.x;
    const int lane = t & 63, wid = t >> 6;
    const int frow = lane & 15, kgrp = lane >> 4;
    const int d = blockIdx.x * 4 + wid;
    if (d >= N) return;
    const int lo = offd[d], hi = offd[d + 1];
    const int deg = hi - lo;

    // A-frags: G[d], rows = heads (rows 8-15 overrun into G[d+1] pad; discarded)
    short8 afr[4];
#pragma unroll
    for (int ks = 0; ks < 4; ++ks)
        afr[ks] = *reinterpret_cast<const short8*>(
            &G[(size_t)d * 1024 + frow * 128 + ks * 32 + kgrp * 8]);

    float y[16] = {};          // [h*2 + c]: col 2*lane+c of head h (unnormalized)
    float den_acc[4] = {};

    for (int tb = 0; tb < deg; tb += 16) {
        int ei = tb + frow;
        int sv = (ei < deg) ? src_d[lo + ei] : 0;

        f32x4 c = {};
#pragma unroll
        for (int ks = 0; ks < 4; ++ks) {
            short8 bfr = *reinterpret_cast<const short8*>(
                &featbf[(size_t)sv * 128 + ks * 32 + kgrp * 8]);
            c = __builtin_amdgcn_mfma_f32_16x16x32_bf16(afr[ks], bfr, c, 0, 0, 0);
        }

        float exr[4];
#pragma unroll
        for (int r = 0; r < 4; ++r) {
            float u = fminf(fmaxf(c[r], -5.f), 5.f);
            exr[r] = __expf(u);
        }
        if (kgrp < 2)
            *reinterpret_cast<float4*>(&exl[wid][frow][kgrp * 4]) =
                float4{exr[0], exr[1], exr[2], exr[3]};
        if (kgrp == 0) srcl[wid][frow] = sv;
#pragma unroll
        for (int r = 0; r < 4; ++r) {
            float v = (ei < deg) ? exr[r] : 0.f;
            v += __shfl_xor(v, 1); v += __shfl_xor(v, 2);
            v += __shfl_xor(v, 4); v += __shfl_xor(v, 8);
            den_acc[r] += v;
        }

        int vc = min(16, deg - tb);
        for (int i = 0; i < vc; ++i) {
            int s = srcl[wid][i];
            float4 e0 = *reinterpret_cast<const float4*>(&exl[wid][i][0]);
            float4 e1 = *reinterpret_cast<const float4*>(&exl[wid][i][4]);
            uint fv = reinterpret_cast<const uint*>(featbf)[(size_t)s * 64 + lane];
            float fx = bf_lo(fv), fy = bf_hi(fv);
            y[0]  += e0.x * fx; y[1]  += e0.x * fy;
            y[2]  += e0.y * fx; y[3]  += e0.y * fy;
            y[4]  += e0.z * fx; y[5]  += e0.z * fy;
            y[6]  += e0.w * fx; y[7]  += e0.w * fy;
            y[8]  += e1.x * fx; y[9]  += e1.x * fy;
            y[10] += e1.y * fx; y[11] += e1.y * fy;
            y[12] += e1.z * fx; y[13] += e1.z * fy;
            y[14] += e1.w * fx; y[15] += e1.w * fy;
        }
    }

    // scale by 1/den_h, write Y row (guard empty dst)
#pragma unroll
    for (int h = 0; h < 8; ++h) {
        float dh = __shfl(den_acc[h & 3], (h & 4) << 2);
        float rd = (dh > 0.f) ? 1.f / dh : 0.f;
        ushort2 o;
        o.x = f2bf(y[2 * h] * rd);
        o.y = f2bf(y[2 * h + 1] * rd);
        reinterpret_cast<ushort2*>(Y)[(size_t)d * 512 + h * 64 + lane] = o;
    }
}

// ---------------------------------------------------------------------------
// bf16 MFMA GEMM (BK=64 loop): C = A @ BT^T [+bias][relu][+res]
// ---------------------------------------------------------------------------
template <int NTILE, typename OT, bool BIAS, bool RELU, bool RES>
__global__ __launch_bounds__(256) void gemm_mfma(
    const ushort* __restrict__ A, const ushort* __restrict__ BT,
    const float* __restrict__ bias, const float* __restrict__ res,
    OT* __restrict__ C, int M, int K, int NC)
{
    constexpr int FN = NTILE * 2;
    constexpr int WN = NTILE * 32;
    __shared__ char lds[16384 + NTILE * 8192];
    char* AsB = lds;
    char* BsB = lds + 16384;

    const int m0 = blockIdx.y * 128;
    const int n0 = blockIdx.x * (NTILE * 64);
    const int t = threadIdx.x;
    const int lane = t & 63, wid = t >> 6;
    const int wm = wid >> 1, wn = wid & 1;
    const int frow = lane & 15, kgrp = lane >> 4;

    f32x4 acc[4][FN] = {};

    for (int kk = 0; kk < K; kk += 64) {
#pragma unroll
        for (int it = 0; it < 4; ++it) {
            int q = it * 256 + t;
            int r = q >> 3, c8 = (q & 7) * 8;
            int gm = m0 + r;
            short8 v = {};
            if (gm < M) v = *reinterpret_cast<const short8*>(&A[(size_t)gm * K + kk + c8]);
            *reinterpret_cast<short8*>(&AsB[r * 128 + ((c8 * 2) ^ ((r & 7) << 4))]) = v;
        }
#pragma unroll
        for (int it = 0; it < 2 * NTILE; ++it) {
            int q = it * 256 + t;
            int r = q >> 3, c8 = (q & 7) * 8;
            short8 v = *reinterpret_cast<const short8*>(&BT[(size_t)(n0 + r) * K + kk + c8]);
            *reinterpret_cast<short8*>(&BsB[r * 128 + ((c8 * 2) ^ ((r & 7) << 4))]) = v;
        }
        __syncthreads();
#pragma unroll
        for (int kp = 0; kp < 2; ++kp) {
            const int koffb = kp * 64 + kgrp * 16;
            short8 b[FN];
#pragma unroll
            for (int fn = 0; fn < FN; ++fn) {
                int col = wn * WN + fn * 16 + frow;
                b[fn] = *reinterpret_cast<const short8*>(&BsB[col * 128 + (koffb ^ ((col & 7) << 4))]);
            }
#pragma unroll
            for (int fm = 0; fm < 4; ++fm) {
                int row = wm * 64 + fm * 16 + frow;
                short8 a = *reinterpret_cast<const short8*>(&AsB[row * 128 + (koffb ^ ((row & 7) << 4))]);
#pragma unroll
                for (int fn = 0; fn < FN; ++fn)
                    acc[fm][fn] = __builtin_amdgcn_mfma_f32_16x16x32_bf16(a, b[fn], acc[fm][fn], 0, 0, 0);
            }
        }
        __syncthreads();
    }

#pragma unroll
    for (int fm = 0; fm < 4; ++fm)
#pragma unroll
        for (int fn = 0; fn < FN; ++fn)
#pragma unroll
            for (int r = 0; r < 4; ++r) {
                int gm = m0 + wm * 64 + fm * 16 + kgrp * 4 + r;
                int gn = n0 + wn * WN + fn * 16 + frow;
                if (gm >= M) continue;
                float v = acc[fm][fn][r];
                if (BIAS) v += bias[gn];
                if (RELU) v = fmaxf(v, 0.f);
                if (RES) v += res[(size_t)gm * NC + gn];
                stC(&C[(size_t)gm * NC + gn], v);
            }
}

// ---------------------------------------------------------------------------
// 64x64-tile GEMM (K loop): [+bias]+res epilogue, fp32 out. Used for the
// Y@P gemm (BIAS=false, res=feat) and f2 (BIAS=true, res=uh).
// ---------------------------------------------------------------------------
template <bool BIAS>
__global__ __launch_bounds__(256) void gemm_mfma64(
    const ushort* __restrict__ A, const ushort* __restrict__ BT,
    const float* __restrict__ bias, const float* __restrict__ res,
    float* __restrict__ C, int M, int K, int NC)
{
    __shared__ char lds[16384];
    char* AsB = lds;
    char* BsB = lds + 8192;

    const int m0 = blockIdx.y * 64;
    const int n0 = blockIdx.x * 64;
    const int t = threadIdx.x;
    const int lane = t & 63, wid = t >> 6;
    const int wm = wid >> 1, wn = wid & 1;
    const int frow = lane & 15, kgrp = lane >> 4;

    f32x4 acc[2][2] = {};

    for (int kk = 0; kk < K; kk += 64) {
#pragma unroll
        for (int it = 0; it < 2; ++it) {
            int q = it * 256 + t;
            int r = q >> 3, c8 = (q & 7) * 8;
            int gm = m0 + r;
            short8 v = {};
            if (gm < M) v = *reinterpret_cast<const short8*>(&A[(size_t)gm * K + kk + c8]);
            *reinterpret_cast<short8*>(&AsB[r * 128 + ((c8 * 2) ^ ((r & 7) << 4))]) = v;
        }
#pragma unroll
        for (int it = 0; it < 2; ++it) {
            int q = it * 256 + t;
            int r = q >> 3, c8 = (q & 7) * 8;
            short8 v = *reinterpret_cast<const short8*>(&BT[(size_t)(n0 + r) * K + kk + c8]);
            *reinterpret_cast<short8*>(&BsB[r * 128 + ((c8 * 2) ^ ((r & 7) << 4))]) = v;
        }
        __syncthreads();
#pragma unroll
        for (int kp = 0; kp < 2; ++kp) {
            const int koffb = kp * 64 + kgrp * 16;
            short8 b[2];
#pragma unroll
            for (int fn = 0; fn < 2; ++fn) {
                int col = wn * 32 + fn * 16 + frow;
                b[fn] = *reinterpret_cast<const short8*>(&BsB[col * 128 + (koffb ^ ((col & 7) << 4))]);
            }
#pragma unroll
            for (int fm = 0; fm < 2; ++fm) {
                int row = wm * 32 + fm * 16 + frow;
                short8 a = *reinterpret_cast<const short8*>(&AsB[row * 128 + (koffb ^ ((row & 7) << 4))]);
#pragma unroll
                for (int fn = 0; fn < 2; ++fn)
                    acc[fm][fn] = __builtin_amdgcn_mfma_f32_16x16x32_bf16(a, b[fn], acc[fm][fn], 0, 0, 0);
            }
        }
        __syncthreads();
    }

#pragma unroll
    for (int fm = 0; fm < 2; ++fm)
#pragma unroll
        for (int fn = 0; fn < 2; ++fn)
#pragma unroll
            for (int r = 0; r < 4; ++r) {
                int gm = m0 + wm * 32 + fm * 16 + kgrp * 4 + r;
                int gn = n0 + wn * 32 + fn * 16 + frow;
                if (gm >= M) continue;
                float v = acc[fm][fn][r] + res[(size_t)gm * NC + gn];
                if (BIAS) v += bias[gn];
                C[(size_t)gm * NC + gn] = v;
            }
}

// ---------------------------------------------------------------------------
// LayerNorm; optional bf16 side-output.
// ---------------------------------------------------------------------------
template <bool BFOUT>
__global__ __launch_bounds__(256) void ln_kernel(
    const float* __restrict__ x, const float* __restrict__ g,
    const float* __restrict__ b, float* __restrict__ out,
    ushort* __restrict__ outbf, int M)
{
    int row = (int)((blockIdx.x * 256 + threadIdx.x) >> 6);
    int lane = threadIdx.x & 63;
    if (row >= M) return;
    float2 v = reinterpret_cast<const float2*>(x)[(size_t)row * 64 + lane];
    float sum = v.x + v.y;
#pragma unroll
    for (int off = 32; off; off >>= 1) sum += __shfl_xor(sum, off);
    float mean = sum * (1.f / 128.f);
    float cx = v.x - mean, cy = v.y - mean;
    float vs = cx * cx + cy * cy;
#pragma unroll
    for (int off = 32; off; off >>= 1) vs += __shfl_xor(vs, off);
    float r = rsqrtf(vs * (1.f / 128.f) + 1e-5f);
    float2 gg = reinterpret_cast<const float2*>(g)[lane];
    float2 bb = reinterpret_cast<const float2*>(b)[lane];
    float2 o;
    o.x = cx * r * gg.x + bb.x;
    o.y = cy * r * gg.y + bb.y;
    reinterpret_cast<float2*>(out)[(size_t)row * 64 + lane] = o;
    if (BFOUT) {
        ushort2 ob; ob.x = f2bf(o.x); ob.y = f2bf(o.y);
        reinterpret_cast<ushort2*>(outbf)[(size_t)row * 64 + lane] = ob;
    }
}

// ---------------------------------------------------------------------------
extern "C" void kernel_launch(void* const* d_in, const int* in_sizes, int n_in,
                              void* d_out, int out_size, void* d_ws, size_t ws_size,
                              hipStream_t stream)
{
    const float* feat = (const float*)d_in[0];
    const int*   src  = (const int*)d_in[1];
    const int*   dst  = (const int*)d_in[2];
    const float* Wq   = (const float*)d_in[3];
    const float* Wk   = (const float*)d_in[4];
    const float* Wv   = (const float*)d_in[5];
    const float* Wo   = (const float*)d_in[6];
    const float* g1   = (const float*)d_in[7];
    const float* b1   = (const float*)d_in[8];
    const float* W1   = (const float*)d_in[9];
    const float* bf1  = (const float*)d_in[10];
    const float* W2   = (const float*)d_in[11];
    const float* bf2  = (const float*)d_in[12];
    const float* g2   = (const float*)d_in[13];
    const float* b2   = (const float*)d_in[14];
    const int N = in_sizes[0] / 128;
    const int E = in_sizes[1];
    float* out = (float*)d_out;

    char* w = (char*)d_ws;
    auto alloc = [&](size_t bytes) {
        char* p = w;
        w += (bytes + 255) & ~(size_t)255;
        return p;
    };
    ushort* MG     = (ushort*)alloc((size_t)1024 * 128 * 2);
    ushort* PT     = (ushort*)alloc((size_t)128 * 1024 * 2);
    float*  WoT    = (float*)alloc((size_t)128 * 1024 * 4);
    ushort* W1T    = (ushort*)alloc((size_t)512 * 128 * 2);
    ushort* W2T    = (ushort*)alloc((size_t)128 * 512 * 2);
    ushort* featbf = (ushort*)alloc((size_t)N * 128 * 2);
    ushort* G      = (ushort*)alloc(((size_t)N * 1024 + 2048) * 2);  // +pad for frow overrun
    ushort* Y      = (ushort*)alloc((size_t)N * 1024 * 2);
    int*    cntd   = (int*)alloc((size_t)((N + 3) & ~3) * 4);
    int*    offd   = (int*)alloc((size_t)(N + 1) * 4);
    int*    curd   = (int*)alloc((size_t)N * 4);
    int*    src_d  = (int*)alloc((size_t)E * 4);
    float*  pre1   = (float*)alloc((size_t)N * 128 * 4);
    float*  uh     = (float*)alloc((size_t)N * 128 * 4);
    ushort* uhbf   = (ushort*)alloc((size_t)N * 128 * 2);
    ushort* f1     = (ushort*)alloc((size_t)N * 512 * 2);
    float*  pre2   = (float*)alloc((size_t)N * 128 * 4);

    // --- K1: prep (zero cntd + f2bf + 3 transposes) ---
    int nz = (N + 3) / 4;
    int zb = (nz + 255) / 256;
    int nf = (N * 32 + 255) / 256;
    prep1_kernel<<<zb + nf + 64, 256, 0, stream>>>(
        (int4*)cntd, nz, feat, featbf, Wo, WoT, W1, W1T, W2, W2T, N);

    // --- K2: histogram + MG/PT build ---
    int eb = (E + 255) / 256;
    hist_mpt_kernel<<<eb + 16, 256, 0, stream>>>(
        dst, cntd, E, eb, Wq, Wk, Wv, WoT, MG, PT);

    // --- K3: CSR scan ---
    scan1_kernel<<<1, 1024, 0, stream>>>(cntd, offd, curd, N);

    // --- K4: G gemm (nbg blocks) + scatter (eb blocks, parallel filler) ---
    int nbg = 8 * ((N + 127) / 128);
    gvo_scat_kernel<<<nbg + eb, 256, 0, stream>>>(
        featbf, MG, G, N, nbg, src, dst, curd, src_d, E);

    // --- K5: fused edge phase (MFMA logits + den + Y accumulation) ---
    edge_fused_kernel<<<(N + 3) / 4, 256, 0, stream>>>(
        featbf, G, src_d, offd, Y, N);

    // --- K6: agg = Y @ [P_h] + feat  (fp32 pre1) ---
    dim3 yg_grid(128 / 64, (N + 63) / 64);
    gemm_mfma64<false><<<yg_grid, 256, 0, stream>>>(
        Y, PT, nullptr, feat, pre1, N, 1024, 128);

    // --- K7: LN1 (fp32 uh + bf16 uhbf) ---
    int nwaves_n = (N * 64 + 255) / 256;
    ln_kernel<true><<<nwaves_n, 256, 0, stream>>>(pre1, g1, b1, uh, uhbf, N);

    // --- K8/K9/K10: FFN + LN2 ---
    dim3 f1_grid(512 / 128, (N + 127) / 128);
    gemm_mfma<2, ushort, true, true, false><<<f1_grid, 256, 0, stream>>>(
        uhbf, W1T, bf1, nullptr, f1, N, 128, 512);
    dim3 f2_grid(128 / 64, (N + 63) / 64);
    gemm_mfma64<true><<<f2_grid, 256, 0, stream>>>(
        f1, W2T, bf2, uh, pre2, N, 512, 128);
    ln_kernel<false><<<nwaves_n, 256, 0, stream>>>(pre2, g2, b2, out, nullptr, N);
}

// Round 18
// 122.913 us; speedup vs baseline: 1.0375x; 1.0375x over previous
//
#include <hip/hip_runtime.h>

typedef unsigned int uint;
typedef unsigned short ushort;
typedef __attribute__((ext_vector_type(8))) short short8;
typedef __attribute__((ext_vector_type(4))) float f32x4;

#define DEV static __device__ __forceinline__

DEV float bf_lo(uint v) { return __uint_as_float(v << 16); }
DEV float bf_hi(uint v) { return __uint_as_float(v & 0xffff0000u); }
DEV ushort f2bf(float f) {
    uint u = __float_as_uint(f);
    u += 0x7fffu + ((u >> 16) & 1u);   // round-to-nearest-even
    return (ushort)(u >> 16);
}
DEV void stC(float* p, float v) { *p = v; }
DEV void stC(ushort* p, float v) { *p = f2bf(v); }

// VALU-speed cross-lane add via DPP (ctrl must be a literal)
#define DPPADD(v, ctrl) \
    ((v) + __int_as_float(__builtin_amdgcn_mov_dpp(__float_as_int(v), (ctrl), 0xF, 0xF, true)))

// ---------------------------------------------------------------------------
// 64x64 tiled transpose body (in fp32 [R][C] -> out [C][R] fp32/bf16)
// ---------------------------------------------------------------------------
template <typename OT>
DEV void transp_body(float (*tile)[65], const float* __restrict__ in,
                     OT* __restrict__ out, int R, int C, int bid, int t)
{
    const int nbx = C >> 6;
    const int bx = bid % nbx, by = bid / nbx;
#pragma unroll
    for (int it = 0; it < 4; ++it) {
        int idx = it * 256 + t;
        int rr = idx >> 4, cc4 = (idx & 15) * 4;
        float4 v = *reinterpret_cast<const float4*>(in + (size_t)(by * 64 + rr) * C + bx * 64 + cc4);
        tile[cc4][rr] = v.x; tile[cc4 + 1][rr] = v.y;
        tile[cc4 + 2][rr] = v.z; tile[cc4 + 3][rr] = v.w;
    }
    __syncthreads();
#pragma unroll
    for (int it = 0; it < 4; ++it) {
        int idx = it * 256 + t;
        int cc = idx >> 4, rr4 = (idx & 15) * 4;
        OT* po = out + (size_t)(bx * 64 + cc) * R + by * 64 + rr4;
        if constexpr (__is_same(OT, float)) {
            float4 o = { tile[cc][rr4], tile[cc][rr4 + 1], tile[cc][rr4 + 2], tile[cc][rr4 + 3] };
            *reinterpret_cast<float4*>(po) = o;
        } else {
            ushort4 o = { f2bf(tile[cc][rr4]), f2bf(tile[cc][rr4 + 1]),
                          f2bf(tile[cc][rr4 + 2]), f2bf(tile[cc][rr4 + 3]) };
            *reinterpret_cast<ushort4*>(po) = o;
        }
    }
}

// ---------------------------------------------------------------------------
// Prep stage 1: [zero cntd] [f2bf feat] [transp Wo] [transp W1] [transp W2]
// ---------------------------------------------------------------------------
__global__ __launch_bounds__(256) void prep1_kernel(
    int4* __restrict__ cntd4, int nz,
    const float* __restrict__ feat, ushort* __restrict__ featbf,
    const float* __restrict__ Wo, float* __restrict__ WoT,
    const float* __restrict__ W1, ushort* __restrict__ W1T,
    const float* __restrict__ W2, ushort* __restrict__ W2T, int N)
{
    __shared__ float tile[64][65];
    const int zb = (nz + 255) / 256;
    const int nf = (N * 32 + 255) / 256;
    const int b = blockIdx.x, t = threadIdx.x;
    if (b < zb) {
        int i = b * 256 + t;
        if (i < nz) cntd4[i] = int4{0, 0, 0, 0};
    } else if (b < zb + nf) {
        int i = (b - zb) * 256 + t;
        if (i >= N * 32) return;
        float4 v = reinterpret_cast<const float4*>(feat)[i];
        ushort4 o;
        o.x = f2bf(v.x); o.y = f2bf(v.y); o.z = f2bf(v.z); o.w = f2bf(v.w);
        reinterpret_cast<ushort4*>(featbf)[i] = o;
    } else if (b < zb + nf + 32) {
        transp_body<float>(tile, Wo, WoT, 1024, 128, b - zb - nf, t);
    } else if (b < zb + nf + 48) {
        transp_body<ushort>(tile, W1, W1T, 128, 512, b - zb - nf - 32, t);
    } else {
        transp_body<ushort>(tile, W2, W2T, 512, 128, b - zb - nf - 48, t);
    }
}

// ---------------------------------------------------------------------------
// Merged: [hist: dst histogram] blocks [0,eb) + [mpt: MFMA M|P build] 16 blocks
// ---------------------------------------------------------------------------
__global__ __launch_bounds__(256) void hist_mpt_kernel(
    const int* __restrict__ dst, int* __restrict__ cntd, int E, int eb,
    const float* __restrict__ Wq, const float* __restrict__ Wk,
    const float* __restrict__ Wv, const float* __restrict__ WoT,
    ushort* __restrict__ MPT)
{
    __shared__ char lds[65536];
    const int b = blockIdx.x, t = threadIdx.x;
    if (b < eb) {
        int e = b * 256 + t;
        if (e < E) atomicAdd(&cntd[dst[e]], 1);
        return;
    }
    char* As = lds;            // 128 rows(j) x 256B (128 bf16), XOR swizzled
    char* Bs = lds + 32768;    // 128 rows(i) x 256B

    const int mb = b - eb;
    const int part = mb >> 3, h = mb & 7;
    const int lane = t & 63, w = t >> 6;
    const int frow = lane & 15, kgrp = lane >> 4;

    const float* Asrc = part ? WoT : Wk;
    const float* Bsrc = part ? Wv : Wq;
    const float ascale = part ? 1.f : 0.08838834764831845f;

#pragma unroll
    for (int it = 0; it < 16; ++it) {
        int idx = it * 256 + t;
        int r = idx >> 5, c4 = (idx & 31) * 4;
        size_t goff = (size_t)r * 1024 + h * 128 + c4;
        float4 va = *reinterpret_cast<const float4*>(Asrc + goff);
        ushort4 ua = { f2bf(va.x * ascale), f2bf(va.y * ascale),
                       f2bf(va.z * ascale), f2bf(va.w * ascale) };
        *reinterpret_cast<ushort4*>(&As[r * 256 + ((c4 * 2) ^ ((r & 7) << 4))]) = ua;
        float4 vb = *reinterpret_cast<const float4*>(Bsrc + goff);
        ushort4 ub = { f2bf(vb.x), f2bf(vb.y), f2bf(vb.z), f2bf(vb.w) };
        *reinterpret_cast<ushort4*>(&Bs[r * 256 + ((c4 * 2) ^ ((r & 7) << 4))]) = ub;
    }
    __syncthreads();

    f32x4 acc[2][8] = {};
#pragma unroll
    for (int ks = 0; ks < 4; ++ks) {
        int koff = ks * 64 + kgrp * 16;
        short8 bfr[8];
#pragma unroll
        for (int fn = 0; fn < 8; ++fn) {
            int col = fn * 16 + frow;
            bfr[fn] = *reinterpret_cast<const short8*>(&Bs[col * 256 + (koff ^ ((col & 7) << 4))]);
        }
#pragma unroll
        for (int fm = 0; fm < 2; ++fm) {
            int row = w * 32 + fm * 16 + frow;
            short8 a = *reinterpret_cast<const short8*>(&As[row * 256 + (koff ^ ((row & 7) << 4))]);
#pragma unroll
            for (int fn = 0; fn < 8; ++fn)
                acc[fm][fn] = __builtin_amdgcn_mfma_f32_16x16x32_bf16(a, bfr[fn], acc[fm][fn], 0, 0, 0);
        }
    }

    const size_t base = ((size_t)part * 1024 + h * 128) * 128;
#pragma unroll
    for (int fm = 0; fm < 2; ++fm)
#pragma unroll
        for (int fn = 0; fn < 8; ++fn)
#pragma unroll
            for (int r = 0; r < 4; ++r) {
                int j = w * 32 + fm * 16 + kgrp * 4 + r;
                int i = fn * 16 + frow;
                MPT[base + (size_t)j * 128 + i] = f2bf(acc[fm][fn][r]);
            }
}

// ---------------------------------------------------------------------------
// CSR scan (dst only), 1024 threads
// ---------------------------------------------------------------------------
__global__ __launch_bounds__(1024) void scan1_kernel(
    const int* __restrict__ cntd, int* __restrict__ offd, int* __restrict__ curd, int N)
{
    __shared__ int ls[1024];
    const int t = threadIdx.x;
    const int chunk = (N + 1023) >> 10;
    int base = t * chunk;
    int s = 0;
    for (int i = 0; i < chunk; ++i) {
        int idx = base + i;
        if (idx < N) s += cntd[idx];
    }
    ls[t] = s;
    __syncthreads();
    for (int d = 1; d < 1024; d <<= 1) {
        int v = (t >= d) ? ls[t - d] : 0;
        __syncthreads();
        ls[t] += v;
        __syncthreads();
    }
    int run = t ? ls[t - 1] : 0;
    for (int i = 0; i < chunk; ++i) {
        int idx = base + i;
        if (idx < N) {
            offd[idx] = run;
            curd[idx] = run;
            run += cntd[idx];
        }
    }
    if (t == 1023) offd[N] = run;
}

// ---------------------------------------------------------------------------
// Merged: [GVO gemm: blocks [0,nbg)] + [scat: blocks [nbg, nbg+eb)].
// GEMM first (long pole starts immediately); scat blocks are trivial parallel
// filler work (NOT a serial tail — R11's scan-merge lesson).
// GVO: C(M,2048) = A(M,128) @ BT(2048,128)^T, BK=64 loop, 128x128 tile.
// ---------------------------------------------------------------------------
__global__ __launch_bounds__(256) void gvo_scat_kernel(
    const ushort* __restrict__ A, const ushort* __restrict__ BT,
    ushort* __restrict__ C, int M, int nbg,
    const int* __restrict__ src, const int* __restrict__ dst,
    int* __restrict__ curd, int* __restrict__ src_d, int* __restrict__ dst_d, int E)
{
    __shared__ char lds[32768];
    const int b = blockIdx.x, t = threadIdx.x;

    if (b >= nbg) {
        int e = (b - nbg) * 256 + t;
        if (e >= E) return;
        int s = src[e], d = dst[e];
        int pd = atomicAdd(&curd[d], 1);
        src_d[pd] = s;
        dst_d[pd] = d;
        return;
    }

    // --- GVO gemm (K=128, NC=2048, 128x128 tile, BK=64) ---
    char* AsB = lds;            // 128 rows x 128B, XOR swizzled
    char* BsB = lds + 16384;    // 128 rows x 128B
    const int m0 = (b >> 4) * 128;
    const int n0 = (b & 15) * 128;
    const int lane = t & 63, wid = t >> 6;
    const int wm = wid >> 1, wn = wid & 1;
    const int frow = lane & 15, kgrp = lane >> 4;

    f32x4 acc[4][4] = {};

    for (int kk = 0; kk < 128; kk += 64) {
#pragma unroll
        for (int it = 0; it < 4; ++it) {
            int q = it * 256 + t;
            int r = q >> 3, c8 = (q & 7) * 8;
            int gm = m0 + r;
            short8 v = {};
            if (gm < M) v = *reinterpret_cast<const short8*>(&A[(size_t)gm * 128 + kk + c8]);
            *reinterpret_cast<short8*>(&AsB[r * 128 + ((c8 * 2) ^ ((r & 7) << 4))]) = v;
        }
#pragma unroll
        for (int it = 0; it < 4; ++it) {
            int q = it * 256 + t;
            int r = q >> 3, c8 = (q & 7) * 8;
            short8 v = *reinterpret_cast<const short8*>(&BT[(size_t)(n0 + r) * 128 + kk + c8]);
            *reinterpret_cast<short8*>(&BsB[r * 128 + ((c8 * 2) ^ ((r & 7) << 4))]) = v;
        }
        __syncthreads();
#pragma unroll
        for (int kp = 0; kp < 2; ++kp) {
            const int koffb = kp * 64 + kgrp * 16;
            short8 bb[4];
#pragma unroll
            for (int fn = 0; fn < 4; ++fn) {
                int col = wn * 64 + fn * 16 + frow;
                bb[fn] = *reinterpret_cast<const short8*>(&BsB[col * 128 + (koffb ^ ((col & 7) << 4))]);
            }
#pragma unroll
            for (int fm = 0; fm < 4; ++fm) {
                int row = wm * 64 + fm * 16 + frow;
                short8 a = *reinterpret_cast<const short8*>(&AsB[row * 128 + (koffb ^ ((row & 7) << 4))]);
#pragma unroll
                for (int fn = 0; fn < 4; ++fn)
                    acc[fm][fn] = __builtin_amdgcn_mfma_f32_16x16x32_bf16(a, bb[fn], acc[fm][fn], 0, 0, 0);
            }
        }
        __syncthreads();
    }

#pragma unroll
    for (int fm = 0; fm < 4; ++fm)
#pragma unroll
        for (int fn = 0; fn < 4; ++fn)
#pragma unroll
            for (int r = 0; r < 4; ++r) {
                int gm = m0 + wm * 64 + fm * 16 + kgrp * 4 + r;
                int gn = n0 + wn * 64 + fn * 16 + frow;
                if (gm >= M) continue;
                stC(&C[(size_t)gm * 2048 + gn], acc[fm][fn][r]);
            }
}

// ---------------------------------------------------------------------------
// Fused edge phase: block owns dsts [d0, d0+4) and their edge range.
// Phase 1: logits (16-lane groups over block's edges; G rows L1-hot).
// Phase 2: wave per dst: den + VO gather-accumulate + LayerNorm1.
// ---------------------------------------------------------------------------
__global__ __launch_bounds__(256) void edge_fused_kernel(
    const ushort* __restrict__ featbf, const ushort* __restrict__ GVO,
    const int* __restrict__ src_d, const int* __restrict__ dst_d,
    const int* __restrict__ offd, float* __restrict__ exws,
    const float* __restrict__ feat, const float* __restrict__ g1,
    const float* __restrict__ b1, float* __restrict__ uh,
    ushort* __restrict__ uhbf, int N)
{
    const int d0 = blockIdx.x * 4;
    const int t = threadIdx.x;
    const int blo = offd[d0];
    const int bhi = offd[min(d0 + 4, N)];

    // --- phase 1: logits for this block's edges ---
    {
        int g = t >> 4, li = t & 15;
        for (int p = blo + g; p < bhi; p += 16) {
            int s = src_d[p], d = dst_d[p];
            uint4 f = reinterpret_cast<const uint4*>(featbf)[(size_t)s * 16 + li];
            const uint4* Grow = reinterpret_cast<const uint4*>(GVO) + (size_t)d * 256 + li;
            float sel = 0.f;
#pragma unroll
            for (int h = 0; h < 8; ++h) {
                uint4 gv = Grow[h * 16];
                float pv = bf_lo(gv.x) * bf_lo(f.x) + bf_hi(gv.x) * bf_hi(f.x);
                pv += bf_lo(gv.y) * bf_lo(f.y) + bf_hi(gv.y) * bf_hi(f.y);
                pv += bf_lo(gv.z) * bf_lo(f.z) + bf_hi(gv.z) * bf_hi(f.z);
                pv += bf_lo(gv.w) * bf_lo(f.w) + bf_hi(gv.w) * bf_hi(f.w);
                pv = DPPADD(pv, 0xB1);   // xor 1
                pv = DPPADD(pv, 0x4E);   // xor 2
                pv = DPPADD(pv, 0x141);  // row_half_mirror
                pv = DPPADD(pv, 0x128);  // row_ror:8
                sel = (li == h) ? pv : sel;
            }
            float u = fminf(fmaxf(sel, -5.f), 5.f);
            float ex = __expf(u);
            if (li < 8) exws[(size_t)p * 8 + li] = ex;
        }
    }
    __threadfence_block();
    __syncthreads();

    // --- phase 2: wave per dst ---
    const int lane = t & 63;
    const int d = d0 + (t >> 6);
    if (d >= N) return;
    const int lo = offd[d], hi = offd[d + 1];

    int h = lane & 7;
    float den = 0.f;
    for (int i = lo + (lane >> 3); i < hi; i += 8)
        den += exws[(size_t)i * 8 + h];
    den += __shfl_xor(den, 8);
    den += __shfl_xor(den, 16);
    den += __shfl_xor(den, 32);
    float rh = 1.f / den;
    float rv0 = __shfl(rh, 0), rv1 = __shfl(rh, 1), rv2 = __shfl(rh, 2), rv3 = __shfl(rh, 3);
    float rv4 = __shfl(rh, 4), rv5 = __shfl(rh, 5), rv6 = __shfl(rh, 6), rv7 = __shfl(rh, 7);

    float acc0 = 0.f, acc1 = 0.f;
    int snext = (lo < hi) ? src_d[lo] : 0;
    for (int i = lo; i < hi; ++i) {
        int s = snext;
        if (i + 1 < hi) snext = src_d[i + 1];
        float4 e0 = *reinterpret_cast<const float4*>(&exws[(size_t)i * 8]);
        float4 e1 = *reinterpret_cast<const float4*>(&exws[(size_t)i * 8 + 4]);
        const uint* vrow = reinterpret_cast<const uint*>(GVO + (size_t)s * 2048 + 1024);
        uint gv0 = vrow[0 * 64 + lane], gv1 = vrow[1 * 64 + lane];
        uint gv2 = vrow[2 * 64 + lane], gv3 = vrow[3 * 64 + lane];
        uint gv4 = vrow[4 * 64 + lane], gv5 = vrow[5 * 64 + lane];
        uint gv6 = vrow[6 * 64 + lane], gv7 = vrow[7 * 64 + lane];
        float a0 = e0.x * rv0, a1 = e0.y * rv1, a2 = e0.z * rv2, a3 = e0.w * rv3;
        float a4 = e1.x * rv4, a5 = e1.y * rv5, a6 = e1.z * rv6, a7 = e1.w * rv7;
        acc0 += a0 * bf_lo(gv0) + a1 * bf_lo(gv1) + a2 * bf_lo(gv2) + a3 * bf_lo(gv3)
              + a4 * bf_lo(gv4) + a5 * bf_lo(gv5) + a6 * bf_lo(gv6) + a7 * bf_lo(gv7);
        acc1 += a0 * bf_hi(gv0) + a1 * bf_hi(gv1) + a2 * bf_hi(gv2) + a3 * bf_hi(gv3)
              + a4 * bf_hi(gv4) + a5 * bf_hi(gv5) + a6 * bf_hi(gv6) + a7 * bf_hi(gv7);
    }

    float2 v = reinterpret_cast<const float2*>(feat)[(size_t)d * 64 + lane];
    v.x += acc0;
    v.y += acc1;
    float sum = v.x + v.y;
#pragma unroll
    for (int off = 32; off; off >>= 1) sum += __shfl_xor(sum, off);
    float mean = sum * (1.f / 128.f);
    float cx = v.x - mean, cy = v.y - mean;
    float vs = cx * cx + cy * cy;
#pragma unroll
    for (int off = 32; off; off >>= 1) vs += __shfl_xor(vs, off);
    float r = rsqrtf(vs * (1.f / 128.f) + 1e-5f);
    float2 gg = reinterpret_cast<const float2*>(g1)[lane];
    float2 bb = reinterpret_cast<const float2*>(b1)[lane];
    float2 o;
    o.x = cx * r * gg.x + bb.x;
    o.y = cy * r * gg.y + bb.y;
    reinterpret_cast<float2*>(uh)[(size_t)d * 64 + lane] = o;
    ushort2 ob; ob.x = f2bf(o.x); ob.y = f2bf(o.y);
    reinterpret_cast<ushort2*>(uhbf)[(size_t)d * 64 + lane] = ob;
}

// ---------------------------------------------------------------------------
// bf16 MFMA GEMM (BK=64 loop): C = A @ BT^T [+bias][relu][+res]
// ---------------------------------------------------------------------------
template <int NTILE, typename OT, bool BIAS, bool RELU, bool RES>
__global__ __launch_bounds__(256) void gemm_mfma(
    const ushort* __restrict__ A, const ushort* __restrict__ BT,
    const float* __restrict__ bias, const float* __restrict__ res,
    OT* __restrict__ C, int M, int K, int NC)
{
    constexpr int FN = NTILE * 2;
    constexpr int WN = NTILE * 32;
    __shared__ char lds[16384 + NTILE * 8192];
    char* AsB = lds;
    char* BsB = lds + 16384;

    const int m0 = blockIdx.y * 128;
    const int n0 = blockIdx.x * (NTILE * 64);
    const int t = threadIdx.x;
    const int lane = t & 63, wid = t >> 6;
    const int wm = wid >> 1, wn = wid & 1;
    const int frow = lane & 15, kgrp = lane >> 4;

    f32x4 acc[4][FN] = {};

    for (int kk = 0; kk < K; kk += 64) {
#pragma unroll
        for (int it = 0; it < 4; ++it) {
            int q = it * 256 + t;
            int r = q >> 3, c8 = (q & 7) * 8;
            int gm = m0 + r;
            short8 v = {};
            if (gm < M) v = *reinterpret_cast<const short8*>(&A[(size_t)gm * K + kk + c8]);
            *reinterpret_cast<short8*>(&AsB[r * 128 + ((c8 * 2) ^ ((r & 7) << 4))]) = v;
        }
#pragma unroll
        for (int it = 0; it < 2 * NTILE; ++it) {
            int q = it * 256 + t;
            int r = q >> 3, c8 = (q & 7) * 8;
            short8 v = *reinterpret_cast<const short8*>(&BT[(size_t)(n0 + r) * K + kk + c8]);
            *reinterpret_cast<short8*>(&BsB[r * 128 + ((c8 * 2) ^ ((r & 7) << 4))]) = v;
        }
        __syncthreads();
#pragma unroll
        for (int kp = 0; kp < 2; ++kp) {
            const int koffb = kp * 64 + kgrp * 16;
            short8 b[FN];
#pragma unroll
            for (int fn = 0; fn < FN; ++fn) {
                int col = wn * WN + fn * 16 + frow;
                b[fn] = *reinterpret_cast<const short8*>(&BsB[col * 128 + (koffb ^ ((col & 7) << 4))]);
            }
#pragma unroll
            for (int fm = 0; fm < 4; ++fm) {
                int row = wm * 64 + fm * 16 + frow;
                short8 a = *reinterpret_cast<const short8*>(&AsB[row * 128 + (koffb ^ ((row & 7) << 4))]);
#pragma unroll
                for (int fn = 0; fn < FN; ++fn)
                    acc[fm][fn] = __builtin_amdgcn_mfma_f32_16x16x32_bf16(a, b[fn], acc[fm][fn], 0, 0, 0);
            }
        }
        __syncthreads();
    }

#pragma unroll
    for (int fm = 0; fm < 4; ++fm)
#pragma unroll
        for (int fn = 0; fn < FN; ++fn)
#pragma unroll
            for (int r = 0; r < 4; ++r) {
                int gm = m0 + wm * 64 + fm * 16 + kgrp * 4 + r;
                int gn = n0 + wn * WN + fn * 16 + frow;
                if (gm >= M) continue;
                float v = acc[fm][fn][r];
                if (BIAS) v += bias[gn];
                if (RELU) v = fmaxf(v, 0.f);
                if (RES) v += res[(size_t)gm * NC + gn];
                stC(&C[(size_t)gm * NC + gn], v);
            }
}

// ---------------------------------------------------------------------------
// 64x64-tile GEMM for f2 (K=512): 314 blocks for occupancy. bias+res epilogue.
// ---------------------------------------------------------------------------
__global__ __launch_bounds__(256) void gemm_mfma64(
    const ushort* __restrict__ A, const ushort* __restrict__ BT,
    const float* __restrict__ bias, const float* __restrict__ res,
    float* __restrict__ C, int M, int K, int NC)
{
    __shared__ char lds[16384];
    char* AsB = lds;
    char* BsB = lds + 8192;

    const int m0 = blockIdx.y * 64;
    const int n0 = blockIdx.x * 64;
    const int t = threadIdx.x;
    const int lane = t & 63, wid = t >> 6;
    const int wm = wid >> 1, wn = wid & 1;
    const int frow = lane & 15, kgrp = lane >> 4;

    f32x4 acc[2][2] = {};

    for (int kk = 0; kk < K; kk += 64) {
#pragma unroll
        for (int it = 0; it < 2; ++it) {
            int q = it * 256 + t;
            int r = q >> 3, c8 = (q & 7) * 8;
            int gm = m0 + r;
            short8 v = {};
            if (gm < M) v = *reinterpret_cast<const short8*>(&A[(size_t)gm * K + kk + c8]);
            *reinterpret_cast<short8*>(&AsB[r * 128 + ((c8 * 2) ^ ((r & 7) << 4))]) = v;
        }
#pragma unroll
        for (int it = 0; it < 2; ++it) {
            int q = it * 256 + t;
            int r = q >> 3, c8 = (q & 7) * 8;
            short8 v = *reinterpret_cast<const short8*>(&BT[(size_t)(n0 + r) * K + kk + c8]);
            *reinterpret_cast<short8*>(&BsB[r * 128 + ((c8 * 2) ^ ((r & 7) << 4))]) = v;
        }
        __syncthreads();
#pragma unroll
        for (int kp = 0; kp < 2; ++kp) {
            const int koffb = kp * 64 + kgrp * 16;
            short8 b[2];
#pragma unroll
            for (int fn = 0; fn < 2; ++fn) {
                int col = wn * 32 + fn * 16 + frow;
                b[fn] = *reinterpret_cast<const short8*>(&BsB[col * 128 + (koffb ^ ((col & 7) << 4))]);
            }
#pragma unroll
            for (int fm = 0; fm < 2; ++fm) {
                int row = wm * 32 + fm * 16 + frow;
                short8 a = *reinterpret_cast<const short8*>(&AsB[row * 128 + (koffb ^ ((row & 7) << 4))]);
#pragma unroll
                for (int fn = 0; fn < 2; ++fn)
                    acc[fm][fn] = __builtin_amdgcn_mfma_f32_16x16x32_bf16(a, b[fn], acc[fm][fn], 0, 0, 0);
            }
        }
        __syncthreads();
    }

#pragma unroll
    for (int fm = 0; fm < 2; ++fm)
#pragma unroll
        for (int fn = 0; fn < 2; ++fn)
#pragma unroll
            for (int r = 0; r < 4; ++r) {
                int gm = m0 + wm * 32 + fm * 16 + kgrp * 4 + r;
                int gn = n0 + wn * 32 + fn * 16 + frow;
                if (gm >= M) continue;
                float v = acc[fm][fn][r] + bias[gn] + res[(size_t)gm * NC + gn];
                C[(size_t)gm * NC + gn] = v;
            }
}

// ---------------------------------------------------------------------------
// Final LayerNorm
// ---------------------------------------------------------------------------
__global__ __launch_bounds__(256) void ln_kernel(
    const float* __restrict__ x, const float* __restrict__ g,
    const float* __restrict__ b, float* __restrict__ out, int M)
{
    int row = (int)((blockIdx.x * 256 + threadIdx.x) >> 6);
    int lane = threadIdx.x & 63;
    if (row >= M) return;
    float2 v = reinterpret_cast<const float2*>(x)[(size_t)row * 64 + lane];
    float sum = v.x + v.y;
#pragma unroll
    for (int off = 32; off; off >>= 1) sum += __shfl_xor(sum, off);
    float mean = sum * (1.f / 128.f);
    float cx = v.x - mean, cy = v.y - mean;
    float vs = cx * cx + cy * cy;
#pragma unroll
    for (int off = 32; off; off >>= 1) vs += __shfl_xor(vs, off);
    float r = rsqrtf(vs * (1.f / 128.f) + 1e-5f);
    float2 gg = reinterpret_cast<const float2*>(g)[lane];
    float2 bb = reinterpret_cast<const float2*>(b)[lane];
    float2 o;
    o.x = cx * r * gg.x + bb.x;
    o.y = cy * r * gg.y + bb.y;
    reinterpret_cast<float2*>(out)[(size_t)row * 64 + lane] = o;
}

// ---------------------------------------------------------------------------
extern "C" void kernel_launch(void* const* d_in, const int* in_sizes, int n_in,
                              void* d_out, int out_size, void* d_ws, size_t ws_size,
                              hipStream_t stream)
{
    const float* feat = (const float*)d_in[0];
    const int*   src  = (const int*)d_in[1];
    const int*   dst  = (const int*)d_in[2];
    const float* Wq   = (const float*)d_in[3];
    const float* Wk   = (const float*)d_in[4];
    const float* Wv   = (const float*)d_in[5];
    const float* Wo   = (const float*)d_in[6];
    const float* g1   = (const float*)d_in[7];
    const float* b1   = (const float*)d_in[8];
    const float* W1   = (const float*)d_in[9];
    const float* bf1  = (const float*)d_in[10];
    const float* W2   = (const float*)d_in[11];
    const float* bf2  = (const float*)d_in[12];
    const float* g2   = (const float*)d_in[13];
    const float* b2   = (const float*)d_in[14];
    const int N = in_sizes[0] / 128;
    const int E = in_sizes[1];
    float* out = (float*)d_out;

    char* w = (char*)d_ws;
    auto alloc = [&](size_t bytes) {
        char* p = w;
        w += (bytes + 255) & ~(size_t)255;
        return p;
    };
    ushort* MPT    = (ushort*)alloc((size_t)2048 * 128 * 2);
    float*  WoT    = (float*)alloc((size_t)128 * 1024 * 4);
    ushort* W1T    = (ushort*)alloc((size_t)512 * 128 * 2);
    ushort* W2T    = (ushort*)alloc((size_t)128 * 512 * 2);
    ushort* featbf = (ushort*)alloc((size_t)N * 128 * 2);
    ushort* GVO    = (ushort*)alloc((size_t)N * 2048 * 2);
    float*  exws   = (float*)alloc((size_t)E * 8 * 4);
    int*    cntd   = (int*)alloc((size_t)((N + 3) & ~3) * 4);
    int*    offd   = (int*)alloc((size_t)(N + 1) * 4);
    int*    curd   = (int*)alloc((size_t)N * 4);
    int*    src_d  = (int*)alloc((size_t)E * 4);
    int*    dst_d  = (int*)alloc((size_t)E * 4);
    float*  uh     = (float*)alloc((size_t)N * 128 * 4);
    ushort* uhbf   = (ushort*)alloc((size_t)N * 128 * 2);
    ushort* f1     = (ushort*)alloc((size_t)N * 512 * 2);
    float*  pre2   = (float*)alloc((size_t)N * 128 * 4);

    // --- K1: prep (zero cntd + f2bf + 3 transposes) ---
    int nz = (N + 3) / 4;
    int zb = (nz + 255) / 256;
    int nf = (N * 32 + 255) / 256;
    prep1_kernel<<<zb + nf + 64, 256, 0, stream>>>(
        (int4*)cntd, nz, feat, featbf, Wo, WoT, W1, W1T, W2, W2T, N);

    // --- K2: histogram (eb blocks) + MPT build (16 blocks) ---
    int eb = (E + 255) / 256;
    hist_mpt_kernel<<<eb + 16, 256, 0, stream>>>(
        dst, cntd, E, eb, Wq, Wk, Wv, WoT, MPT);

    // --- K3: CSR scan (1024 threads, own dispatch — fast serial stage) ---
    scan1_kernel<<<1, 1024, 0, stream>>>(cntd, offd, curd, N);

    // --- K4: GVO gemm (nbg blocks) + scatter (eb blocks, parallel filler) ---
    int nbg = 16 * ((N + 127) / 128);
    gvo_scat_kernel<<<nbg + eb, 256, 0, stream>>>(
        featbf, MPT, GVO, N, nbg, src, dst, curd, src_d, dst_d, E);

    // --- K5: fused edge phase (logits + den + agg + LN1) ---
    edge_fused_kernel<<<(N + 3) / 4, 256, 0, stream>>>(
        featbf, GVO, src_d, dst_d, offd, exws, feat, g1, b1, uh, uhbf, N);

    // --- K6/K7/K8: FFN + LN2 ---
    dim3 f1_grid(512 / 128, (N + 127) / 128);
    gemm_mfma<2, ushort, true, true, false><<<f1_grid, 256, 0, stream>>>(
        uhbf, W1T, bf1, nullptr, f1, N, 128, 512);
    dim3 f2_grid(128 / 64, (N + 63) / 64);
    gemm_mfma64<<<f2_grid, 256, 0, stream>>>(
        f1, W2T, bf2, uh, pre2, N, 512, 128);
    int nwaves_n = (N * 64 + 255) / 256;
    ln_kernel<<<nwaves_n, 256, 0, stream>>>(pre2, g2, b2, out, N);
}